// Round 9
// baseline (94990.894 us; speedup 1.0000x reference)
//
#include <hip/hip_runtime.h>
#include <math.h>

typedef float v2f __attribute__((ext_vector_type(2)));

#define EPSV 1e-5f
#define SBAR() __builtin_amdgcn_sched_barrier(0)

// W2, G3, l1g/l1b/l2g/l2b are stored ROW-REMAPPED in LDS: row r -> slot
// (r&7)*4 + (r>>3), so the 4 lanes of a quad (rows 8p+i) read 16B-apart
// addresses -> conflict-free. W1/G1/G2 stay linear (col-split is 32B-apart).
struct __align__(16) WS {
  float W1[128]; float b1[32]; float W2[128]; float b2[4];
  float G1[128]; float gb1[32]; float l1g[32]; float l1b[32];
  float G2[1024]; float gb2[32]; float l2g[32]; float l2b[32];
  float G3[128]; float gb3[4];
};

// packed a += s * {wx,wy} -> v_pk_fma_f32. v2f ONLY as named locals (R6 lesson).
__device__ __forceinline__ v2f pkfma(float s, float wx, float wy, v2f a) {
  v2f w = {wx, wy};
  v2f sv = {s, s};
  return __builtin_elementwise_fma(sv, w, a);
}

__device__ __forceinline__ float ftanh(float x) {
  // tanh(x) = 1 - 2/(exp(2x)+1); exp->inf => rcp->0 => 1. Asymptotes exact.
  float e = __expf(x + x);
  float r = __builtin_amdgcn_rcpf(e + 1.0f);
  return fmaf(-2.0f, r, 1.0f);
}

// LayerNorm over 32 values held 8-per-lane across a 4-lane quad.
// g/b are row-remapped: my row (8p+i) lives at slot i*4+p.
__device__ __forceinline__ void lnorm8_quad(float* t, const float* g,
                                            const float* b, int p) {
  float s = 0.f, ss = 0.f;
  #pragma unroll
  for (int i = 0; i < 8; ++i) { s += t[i]; ss = fmaf(t[i], t[i], ss); }
  s  += __shfl_xor(s, 1);  ss += __shfl_xor(ss, 1);
  s  += __shfl_xor(s, 2);  ss += __shfl_xor(ss, 2);
  float m = s * 0.03125f;
  float v = fmaf(-m, m, ss * 0.03125f);
  float r = __frsqrt_rn(v + EPSV);
  #pragma unroll
  for (int i = 0; i < 8; ++i) t[i] = fmaf((t[i] - m) * r, g[i * 4 + p], b[i * 4 + p]);
}

// f-eval split across a 4-lane quad: lane p owns cols [8p, 8p+8) of each
// 32-wide layer. Partner t-halves reach G2 via shfl VALUE + partner row base
// in the LDS ADDRESS (rq = r0 ^ 8m) -- no dynamic private-array indexing.
__device__ __forceinline__ void fode4(const WS* w, int p, const float y[4],
                                      float out[4]) {
  const float4* W1v  = (const float4*)w->W1;
  const float4* b1v  = (const float4*)w->b1;
  const float4* W2v  = (const float4*)w->W2;   // row-remapped
  const float4* G1v  = (const float4*)w->G1;
  const float4* gb1v = (const float4*)w->gb1;
  const float4* G2v  = (const float4*)w->G2;
  const float4* gb2v = (const float4*)w->gb2;
  const float4* G3v  = (const float4*)w->G3;   // row-remapped
  const int j0 = 2 * p;   // my float4 col-group base (of 8)
  const int r0 = 8 * p;   // my row base (of 32)

  // ---- magnitude net: partial over my 8 hidden units ----
  v2f m0 = {0.f, 0.f}, m1 = {0.f, 0.f};
  #pragma unroll
  for (int j = 0; j < 2; ++j) {
    float4 bb = b1v[j0 + j];
    v2f a0 = {bb.x, bb.y}, a1 = {bb.z, bb.w};
    #pragma unroll
    for (int i = 0; i < 4; ++i) {
      float4 wv = W1v[i * 8 + j0 + j];
      a0 = pkfma(y[i], wv.x, wv.y, a0);
      a1 = pkfma(y[i], wv.z, wv.w, a1);
    }
    float h0 = ftanh(a0.x), h1 = ftanh(a0.y), h2 = ftanh(a1.x), h3 = ftanh(a1.y);
    // original W2 row (8p + 4j + c) -> remapped slot (4j+c)*4 + p
    float4 w0 = W2v[(4*j + 0) * 4 + p];
    m0 = pkfma(h0, w0.x, w0.y, m0); m1 = pkfma(h0, w0.z, w0.w, m1);
    float4 w1 = W2v[(4*j + 1) * 4 + p];
    m0 = pkfma(h1, w1.x, w1.y, m0); m1 = pkfma(h1, w1.z, w1.w, m1);
    float4 w2 = W2v[(4*j + 2) * 4 + p];
    m0 = pkfma(h2, w2.x, w2.y, m0); m1 = pkfma(h2, w2.z, w2.w, m1);
    float4 w3 = W2v[(4*j + 3) * 4 + p];
    m0 = pkfma(h3, w3.x, w3.y, m0); m1 = pkfma(h3, w3.z, w3.w, m1);
    SBAR();
  }

  // ---- gating layer 1: my 8 of t = LN(tanh(y@G1+gb1)) ----
  float tm[8];
  #pragma unroll
  for (int j = 0; j < 2; ++j) {
    float4 bb = gb1v[j0 + j];
    v2f a0 = {bb.x, bb.y}, a1 = {bb.z, bb.w};
    #pragma unroll
    for (int i = 0; i < 4; ++i) {
      float4 wv = G1v[i * 8 + j0 + j];
      a0 = pkfma(y[i], wv.x, wv.y, a0);
      a1 = pkfma(y[i], wv.z, wv.w, a1);
    }
    tm[4*j+0] = ftanh(a0.x); tm[4*j+1] = ftanh(a0.y);
    tm[4*j+2] = ftanh(a1.x); tm[4*j+3] = ftanh(a1.y);
    SBAR();
  }
  lnorm8_quad(tm, w->l1g, w->l1b, p);

  // ---- gating layer 2: my 8 of u = LN(tanh(t@G2+gb2)) ----
  float um[8];
  {
    float4 bb0 = gb2v[j0], bb1 = gb2v[j0 + 1];
    v2f a00 = {bb0.x, bb0.y}, a01 = {bb0.z, bb0.w};
    v2f a10 = {bb1.x, bb1.y}, a11 = {bb1.z, bb1.w};
    #pragma unroll
    for (int m = 0; m < 4; ++m) {
      const int rq = r0 ^ (8 * m);   // partner (p^m)'s row base -- address only
      #pragma unroll
      for (int i = 0; i < 8; ++i) {
        float s = (m == 0) ? tm[i] : __shfl_xor(tm[i], m);
        float4 w0 = G2v[(rq + i) * 8 + j0];
        a00 = pkfma(s, w0.x, w0.y, a00); a01 = pkfma(s, w0.z, w0.w, a01);
        float4 w1 = G2v[(rq + i) * 8 + j0 + 1];
        a10 = pkfma(s, w1.x, w1.y, a10); a11 = pkfma(s, w1.z, w1.w, a11);
      }
      SBAR();
    }
    um[0] = ftanh(a00.x); um[1] = ftanh(a00.y);
    um[2] = ftanh(a01.x); um[3] = ftanh(a01.y);
    um[4] = ftanh(a10.x); um[5] = ftanh(a10.y);
    um[6] = ftanh(a11.x); um[7] = ftanh(a11.y);
  }
  lnorm8_quad(um, w->l2g, w->l2b, p);

  // ---- G3 partial over my 8 rows, then quad-reduce ----
  v2f z0 = {0.f, 0.f}, z1 = {0.f, 0.f};
  #pragma unroll
  for (int i = 0; i < 8; ++i) {
    float4 wv = G3v[i * 4 + p];   // remapped slot for row 8p+i
    z0 = pkfma(um[i], wv.x, wv.y, z0);
    z1 = pkfma(um[i], wv.z, wv.w, z1);
  }
  SBAR();

  float4 b2v  = *(const float4*)w->b2;
  float4 gb3v = *(const float4*)w->gb3;
  float zx = z0.x, zy = z0.y, zz = z1.x, zw = z1.y;
  float mx = m0.x, my = m0.y, mz = m1.x, mw = m1.y;
  zx += __shfl_xor(zx, 1); zx += __shfl_xor(zx, 2);
  zy += __shfl_xor(zy, 1); zy += __shfl_xor(zy, 2);
  zz += __shfl_xor(zz, 1); zz += __shfl_xor(zz, 2);
  zw += __shfl_xor(zw, 1); zw += __shfl_xor(zw, 2);
  mx += __shfl_xor(mx, 1); mx += __shfl_xor(mx, 2);
  my += __shfl_xor(my, 1); my += __shfl_xor(my, 2);
  mz += __shfl_xor(mz, 1); mz += __shfl_xor(mz, 2);
  mw += __shfl_xor(mw, 1); mw += __shfl_xor(mw, 2);
  zx += gb3v.x; zy += gb3v.y; zz += gb3v.z; zw += gb3v.w;
  out[0] = (mx + b2v.x) * __expf(-zx * zx);
  out[1] = (my + b2v.y) * __expf(-zy * zy);
  out[2] = (mz + b2v.z) * __expf(-zz * zz);
  out[3] = (mw + b2v.w) * __expf(-zw * zw);
}

__global__ __launch_bounds__(256, 4) void ode_kernel(
    const float* __restrict__ s_grid, const float* __restrict__ y0,
    const float* __restrict__ W1, const float* __restrict__ b1,
    const float* __restrict__ W2, const float* __restrict__ b2,
    const float* __restrict__ G1, const float* __restrict__ gb1,
    const float* __restrict__ l1g, const float* __restrict__ l1b,
    const float* __restrict__ G2, const float* __restrict__ gb2,
    const float* __restrict__ l2g, const float* __restrict__ l2b,
    const float* __restrict__ G3, const float* __restrict__ gb3,
    float* __restrict__ out, int T, int B) {
  __shared__ WS w;
  __shared__ float sg[512];
  const int tx = threadIdx.x;

  for (int i = tx; i < 128; i += 256) { w.W1[i] = W1[i]; w.G1[i] = G1[i]; }
  for (int i = tx; i < 1024; i += 256) w.G2[i] = G2[i];
  if (tx < 32) {
    const int d = (tx & 7) * 4 + (tx >> 3);   // row remap
    ((float4*)w.W2)[d] = ((const float4*)W2)[tx];
    ((float4*)w.G3)[d] = ((const float4*)G3)[tx];
    w.l1g[d] = l1g[tx]; w.l1b[d] = l1b[tx];
    w.l2g[d] = l2g[tx]; w.l2b[d] = l2b[tx];
    w.b1[tx] = b1[tx];  w.gb1[tx] = gb1[tx]; w.gb2[tx] = gb2[tx];
  }
  if (tx < 4) { w.b2[tx] = b2[tx]; w.gb3[tx] = gb3[tx]; }
  for (int i = tx; i < T && i < 512; i += 256) sg[i] = s_grid[i];
  __syncthreads();

  const int tid = blockIdx.x * 256 + tx;
  const int sys = tid >> 2;   // one system per 4-lane quad
  const int p   = tid & 3;    // my column/row quarter
  if (sys >= B) return;

  float4 y0v = ((const float4*)y0)[sys];
  float y[4] = {y0v.x, y0v.y, y0v.z, y0v.w};

  // coalesced component store: lane p stores component p at flat idx t*4B+tid
  {
    float yv = (p == 0) ? y[0] : ((p == 1) ? y[1] : ((p == 2) ? y[2] : y[3]));
    out[tid] = yv;
  }

  #pragma unroll 1
  for (int t = 0; t < T - 1; ++t) {
    const float h = sg[t + 1] - sg[t];
    float k[4], ksum[4], yt[4];

    fode4(&w, p, y, k);
    #pragma unroll
    for (int c = 0; c < 4; ++c) { ksum[c] = k[c]; yt[c] = fmaf(0.5f * h, k[c], y[c]); }
    SBAR();
    fode4(&w, p, yt, k);
    #pragma unroll
    for (int c = 0; c < 4; ++c) { ksum[c] = fmaf(2.0f, k[c], ksum[c]); yt[c] = fmaf(0.5f * h, k[c], y[c]); }
    SBAR();
    fode4(&w, p, yt, k);
    #pragma unroll
    for (int c = 0; c < 4; ++c) { ksum[c] = fmaf(2.0f, k[c], ksum[c]); yt[c] = fmaf(h, k[c], y[c]); }
    SBAR();
    fode4(&w, p, yt, k);
    #pragma unroll
    for (int c = 0; c < 4; ++c)
      y[c] = fmaf(h * (1.0f / 6.0f), ksum[c] + k[c], y[c]);

    float yv = (p == 0) ? y[0] : ((p == 1) ? y[1] : ((p == 2) ? y[2] : y[3]));
    out[(size_t)(t + 1) * 4 * B + tid] = yv;
  }
}

extern "C" void kernel_launch(void* const* d_in, const int* in_sizes, int n_in,
                              void* d_out, int out_size, void* d_ws, size_t ws_size,
                              hipStream_t stream) {
  const float* s_grid = (const float*)d_in[0];
  const float* y0     = (const float*)d_in[1];
  const float* W1     = (const float*)d_in[2];
  const float* b1     = (const float*)d_in[3];
  const float* W2     = (const float*)d_in[4];
  const float* b2     = (const float*)d_in[5];
  const float* G1     = (const float*)d_in[6];
  const float* gb1    = (const float*)d_in[7];
  const float* l1g    = (const float*)d_in[8];
  const float* l1b    = (const float*)d_in[9];
  const float* G2     = (const float*)d_in[10];
  const float* gb2    = (const float*)d_in[11];
  const float* l2g    = (const float*)d_in[12];
  const float* l2b    = (const float*)d_in[13];
  const float* G3     = (const float*)d_in[14];
  const float* gb3    = (const float*)d_in[15];

  const int T = in_sizes[0];
  const int B = in_sizes[1] / 4;

  const long long threads = 4LL * B;   // 4 lanes per system -> 4 waves/SIMD
  dim3 block(256);
  dim3 grid((unsigned)((threads + 255) / 256));
  hipLaunchKernelGGL(ode_kernel, grid, block, 0, stream,
                     s_grid, y0, W1, b1, W2, b2, G1, gb1, l1g, l1b,
                     G2, gb2, l2g, l2b, G3, gb3, (float*)d_out, T, B);
}

// Round 10
// 22196.643 us; speedup vs baseline: 4.2795x; 4.2795x over previous
//
#include <hip/hip_runtime.h>
#include <math.h>

typedef float v2f __attribute__((ext_vector_type(2)));

#define EPSV 1e-5f
#define SBAR() __builtin_amdgcn_sched_barrier(0)

// W2, G3, l1g/l1b/l2g/l2b are stored ROW-REMAPPED in LDS: row r -> slot
// (r&7)*4 + (r>>3), so the 4 lanes of a quad (rows 8p+i) read 16B-apart
// addresses -> conflict-free (R9: bank conflicts 1.3e8 -> 2.5e4).
struct __align__(16) WS {
  float W1[128]; float b1[32]; float W2[128]; float b2[4];
  float G1[128]; float gb1[32]; float l1g[32]; float l1b[32];
  float G2[1024]; float gb2[32]; float l2g[32]; float l2b[32];
  float G3[128]; float gb3[4];
};

// packed a += s * {wx,wy} -> v_pk_fma_f32. v2f ONLY as named locals (R6 lesson).
__device__ __forceinline__ v2f pkfma(float s, float wx, float wy, v2f a) {
  v2f w = {wx, wy};
  v2f sv = {s, s};
  return __builtin_elementwise_fma(sv, w, a);
}

__device__ __forceinline__ float ftanh(float x) {
  // tanh(x) = 1 - 2/(exp(2x)+1); exp->inf => rcp->0 => 1. Asymptotes exact.
  float e = __expf(x + x);
  float r = __builtin_amdgcn_rcpf(e + 1.0f);
  return fmaf(-2.0f, r, 1.0f);
}

// LayerNorm over 32 values held 8-per-lane across a 4-lane quad.
// g/b are row-remapped: my row (8p+i) lives at slot i*4+p.
__device__ __forceinline__ void lnorm8_quad(float* t, const float* g,
                                            const float* b, int p) {
  float s = 0.f, ss = 0.f;
  #pragma unroll
  for (int i = 0; i < 8; ++i) { s += t[i]; ss = fmaf(t[i], t[i], ss); }
  s  += __shfl_xor(s, 1);  ss += __shfl_xor(ss, 1);
  s  += __shfl_xor(s, 2);  ss += __shfl_xor(ss, 2);
  float m = s * 0.03125f;
  float v = fmaf(-m, m, ss * 0.03125f);
  float r = __frsqrt_rn(v + EPSV);
  #pragma unroll
  for (int i = 0; i < 8; ++i) t[i] = fmaf((t[i] - m) * r, g[i * 4 + p], b[i * 4 + p]);
}

// f-eval split across a 4-lane quad: lane p owns cols [8p, 8p+8) of each
// 32-wide layer. Partner t-halves reach G2 via shfl VALUE + partner row base
// in the LDS ADDRESS (rq = r0 ^ 8m) -- no dynamic private-array indexing.
__device__ __forceinline__ void fode4(const WS* w, int p, const float y[4],
                                      float out[4]) {
  const float4* W1v  = (const float4*)w->W1;
  const float4* b1v  = (const float4*)w->b1;
  const float4* W2v  = (const float4*)w->W2;   // row-remapped
  const float4* G1v  = (const float4*)w->G1;
  const float4* gb1v = (const float4*)w->gb1;
  const float4* G2v  = (const float4*)w->G2;
  const float4* gb2v = (const float4*)w->gb2;
  const float4* G3v  = (const float4*)w->G3;   // row-remapped
  const int j0 = 2 * p;   // my float4 col-group base (of 8)
  const int r0 = 8 * p;   // my row base (of 32)

  // ---- magnitude net: partial over my 8 hidden units ----
  v2f m0 = {0.f, 0.f}, m1 = {0.f, 0.f};
  #pragma unroll
  for (int j = 0; j < 2; ++j) {
    float4 bb = b1v[j0 + j];
    v2f a0 = {bb.x, bb.y}, a1 = {bb.z, bb.w};
    #pragma unroll
    for (int i = 0; i < 4; ++i) {
      float4 wv = W1v[i * 8 + j0 + j];
      a0 = pkfma(y[i], wv.x, wv.y, a0);
      a1 = pkfma(y[i], wv.z, wv.w, a1);
    }
    float h0 = ftanh(a0.x), h1 = ftanh(a0.y), h2 = ftanh(a1.x), h3 = ftanh(a1.y);
    // original W2 row (8p + 4j + c) -> remapped slot (4j+c)*4 + p
    float4 w0 = W2v[(4*j + 0) * 4 + p];
    m0 = pkfma(h0, w0.x, w0.y, m0); m1 = pkfma(h0, w0.z, w0.w, m1);
    float4 w1 = W2v[(4*j + 1) * 4 + p];
    m0 = pkfma(h1, w1.x, w1.y, m0); m1 = pkfma(h1, w1.z, w1.w, m1);
    float4 w2 = W2v[(4*j + 2) * 4 + p];
    m0 = pkfma(h2, w2.x, w2.y, m0); m1 = pkfma(h2, w2.z, w2.w, m1);
    float4 w3 = W2v[(4*j + 3) * 4 + p];
    m0 = pkfma(h3, w3.x, w3.y, m0); m1 = pkfma(h3, w3.z, w3.w, m1);
    SBAR();
  }

  // ---- gating layer 1: my 8 of t = LN(tanh(y@G1+gb1)) ----
  float tm[8];
  #pragma unroll
  for (int j = 0; j < 2; ++j) {
    float4 bb = gb1v[j0 + j];
    v2f a0 = {bb.x, bb.y}, a1 = {bb.z, bb.w};
    #pragma unroll
    for (int i = 0; i < 4; ++i) {
      float4 wv = G1v[i * 8 + j0 + j];
      a0 = pkfma(y[i], wv.x, wv.y, a0);
      a1 = pkfma(y[i], wv.z, wv.w, a1);
    }
    tm[4*j+0] = ftanh(a0.x); tm[4*j+1] = ftanh(a0.y);
    tm[4*j+2] = ftanh(a1.x); tm[4*j+3] = ftanh(a1.y);
    SBAR();
  }
  lnorm8_quad(tm, w->l1g, w->l1b, p);

  // ---- gating layer 2: my 8 of u = LN(tanh(t@G2+gb2)) ----
  float um[8];
  {
    float4 bb0 = gb2v[j0], bb1 = gb2v[j0 + 1];
    v2f a00 = {bb0.x, bb0.y}, a01 = {bb0.z, bb0.w};
    v2f a10 = {bb1.x, bb1.y}, a11 = {bb1.z, bb1.w};
    #pragma unroll
    for (int m = 0; m < 4; ++m) {
      const int rq = r0 ^ (8 * m);   // partner (p^m)'s row base -- address only
      #pragma unroll
      for (int i = 0; i < 8; ++i) {
        float s = (m == 0) ? tm[i] : __shfl_xor(tm[i], m);
        float4 w0 = G2v[(rq + i) * 8 + j0];
        a00 = pkfma(s, w0.x, w0.y, a00); a01 = pkfma(s, w0.z, w0.w, a01);
        float4 w1 = G2v[(rq + i) * 8 + j0 + 1];
        a10 = pkfma(s, w1.x, w1.y, a10); a11 = pkfma(s, w1.z, w1.w, a11);
      }
      SBAR();
    }
    um[0] = ftanh(a00.x); um[1] = ftanh(a00.y);
    um[2] = ftanh(a01.x); um[3] = ftanh(a01.y);
    um[4] = ftanh(a10.x); um[5] = ftanh(a10.y);
    um[6] = ftanh(a11.x); um[7] = ftanh(a11.y);
  }
  lnorm8_quad(um, w->l2g, w->l2b, p);

  // ---- G3 partial over my 8 rows, then quad-reduce ----
  v2f z0 = {0.f, 0.f}, z1 = {0.f, 0.f};
  #pragma unroll
  for (int i = 0; i < 8; ++i) {
    float4 wv = G3v[i * 4 + p];   // remapped slot for row 8p+i
    z0 = pkfma(um[i], wv.x, wv.y, z0);
    z1 = pkfma(um[i], wv.z, wv.w, z1);
  }
  SBAR();

  float4 b2v  = *(const float4*)w->b2;
  float4 gb3v = *(const float4*)w->gb3;
  float zx = z0.x, zy = z0.y, zz = z1.x, zw = z1.y;
  float mx = m0.x, my = m0.y, mz = m1.x, mw = m1.y;
  zx += __shfl_xor(zx, 1); zx += __shfl_xor(zx, 2);
  zy += __shfl_xor(zy, 1); zy += __shfl_xor(zy, 2);
  zz += __shfl_xor(zz, 1); zz += __shfl_xor(zz, 2);
  zw += __shfl_xor(zw, 1); zw += __shfl_xor(zw, 2);
  mx += __shfl_xor(mx, 1); mx += __shfl_xor(mx, 2);
  my += __shfl_xor(my, 1); my += __shfl_xor(my, 2);
  mz += __shfl_xor(mz, 1); mz += __shfl_xor(mz, 2);
  mw += __shfl_xor(mw, 1); mw += __shfl_xor(mw, 2);
  zx += gb3v.x; zy += gb3v.y; zz += gb3v.z; zw += gb3v.w;
  out[0] = (mx + b2v.x) * __expf(-zx * zx);
  out[1] = (my + b2v.y) * __expf(-zy * zy);
  out[2] = (mz + b2v.z) * __expf(-zz * zz);
  out[3] = (mw + b2v.w) * __expf(-zw * zw);
}

// (256,2): allocator caps at 256 but snaps to the highest occupancy boundary
// that avoids spilling (R5 landed exactly 128). Demand here ~<=110 -> expect
// 128 -> 4 waves/SIMD. (256,4) FORCED cap 64 -> catastrophic spill (R9).
__global__ __launch_bounds__(256, 2) void ode_kernel(
    const float* __restrict__ s_grid, const float* __restrict__ y0,
    const float* __restrict__ W1, const float* __restrict__ b1,
    const float* __restrict__ W2, const float* __restrict__ b2,
    const float* __restrict__ G1, const float* __restrict__ gb1,
    const float* __restrict__ l1g, const float* __restrict__ l1b,
    const float* __restrict__ G2, const float* __restrict__ gb2,
    const float* __restrict__ l2g, const float* __restrict__ l2b,
    const float* __restrict__ G3, const float* __restrict__ gb3,
    float* __restrict__ out, int T, int B) {
  __shared__ WS w;
  __shared__ float sg[512];
  const int tx = threadIdx.x;

  for (int i = tx; i < 128; i += 256) { w.W1[i] = W1[i]; w.G1[i] = G1[i]; }
  for (int i = tx; i < 1024; i += 256) w.G2[i] = G2[i];
  if (tx < 32) {
    const int d = (tx & 7) * 4 + (tx >> 3);   // row remap
    ((float4*)w.W2)[d] = ((const float4*)W2)[tx];
    ((float4*)w.G3)[d] = ((const float4*)G3)[tx];
    w.l1g[d] = l1g[tx]; w.l1b[d] = l1b[tx];
    w.l2g[d] = l2g[tx]; w.l2b[d] = l2b[tx];
    w.b1[tx] = b1[tx];  w.gb1[tx] = gb1[tx]; w.gb2[tx] = gb2[tx];
  }
  if (tx < 4) { w.b2[tx] = b2[tx]; w.gb3[tx] = gb3[tx]; }
  for (int i = tx; i < T && i < 512; i += 256) sg[i] = s_grid[i];
  __syncthreads();

  const int tid = blockIdx.x * 256 + tx;
  const int sys = tid >> 2;   // one system per 4-lane quad
  const int p   = tid & 3;    // my column/row quarter
  if (sys >= B) return;

  float4 y0v = ((const float4*)y0)[sys];
  float y[4] = {y0v.x, y0v.y, y0v.z, y0v.w};

  // coalesced component store: lane p stores component p at flat idx t*4B+tid
  {
    float yv = (p == 0) ? y[0] : ((p == 1) ? y[1] : ((p == 2) ? y[2] : y[3]));
    out[tid] = yv;
  }

  #pragma unroll 1
  for (int t = 0; t < T - 1; ++t) {
    const float h = sg[t + 1] - sg[t];
    float k[4], ksum[4], yt[4];

    fode4(&w, p, y, k);
    #pragma unroll
    for (int c = 0; c < 4; ++c) { ksum[c] = k[c]; yt[c] = fmaf(0.5f * h, k[c], y[c]); }
    SBAR();
    fode4(&w, p, yt, k);
    #pragma unroll
    for (int c = 0; c < 4; ++c) { ksum[c] = fmaf(2.0f, k[c], ksum[c]); yt[c] = fmaf(0.5f * h, k[c], y[c]); }
    SBAR();
    fode4(&w, p, yt, k);
    #pragma unroll
    for (int c = 0; c < 4; ++c) { ksum[c] = fmaf(2.0f, k[c], ksum[c]); yt[c] = fmaf(h, k[c], y[c]); }
    SBAR();
    fode4(&w, p, yt, k);
    #pragma unroll
    for (int c = 0; c < 4; ++c)
      y[c] = fmaf(h * (1.0f / 6.0f), ksum[c] + k[c], y[c]);

    float yv = (p == 0) ? y[0] : ((p == 1) ? y[1] : ((p == 2) ? y[2] : y[3]));
    out[(size_t)(t + 1) * 4 * B + tid] = yv;
  }
}

extern "C" void kernel_launch(void* const* d_in, const int* in_sizes, int n_in,
                              void* d_out, int out_size, void* d_ws, size_t ws_size,
                              hipStream_t stream) {
  const float* s_grid = (const float*)d_in[0];
  const float* y0     = (const float*)d_in[1];
  const float* W1     = (const float*)d_in[2];
  const float* b1     = (const float*)d_in[3];
  const float* W2     = (const float*)d_in[4];
  const float* b2     = (const float*)d_in[5];
  const float* G1     = (const float*)d_in[6];
  const float* gb1    = (const float*)d_in[7];
  const float* l1g    = (const float*)d_in[8];
  const float* l1b    = (const float*)d_in[9];
  const float* G2     = (const float*)d_in[10];
  const float* gb2    = (const float*)d_in[11];
  const float* l2g    = (const float*)d_in[12];
  const float* l2b    = (const float*)d_in[13];
  const float* G3     = (const float*)d_in[14];
  const float* gb3    = (const float*)d_in[15];

  const int T = in_sizes[0];
  const int B = in_sizes[1] / 4;

  const long long threads = 4LL * B;   // 4 lanes per system -> 4 waves/SIMD
  dim3 block(256);
  dim3 grid((unsigned)((threads + 255) / 256));
  hipLaunchKernelGGL(ode_kernel, grid, block, 0, stream,
                     s_grid, y0, W1, b1, W2, b2, G1, gb1, l1g, l1b,
                     G2, gb2, l2g, l2b, G3, gb3, (float*)d_out, T, B);
}

// Round 11
// 6270.794 us; speedup vs baseline: 15.1481x; 3.5397x over previous
//
#include <hip/hip_runtime.h>
#include <math.h>

typedef float v2f __attribute__((ext_vector_type(2)));

#define EPSV 1e-5f
#define SBAR() __builtin_amdgcn_sched_barrier(0)

// W2, G3, l1g/l1b/l2g/l2b are stored ROW-REMAPPED in LDS: row r -> slot
// (r&7)*4 + (r>>3), so the 4 lanes of a quad (rows 8p+i) read 16B-apart
// addresses -> conflict-free (R9/R10: bank conflicts ~2.5e4).
struct __align__(16) WS {
  float W1[128]; float b1[32]; float W2[128]; float b2[4];
  float G1[128]; float gb1[32]; float l1g[32]; float l1b[32];
  float G2[1024]; float gb2[32]; float l2g[32]; float l2b[32];
  float G3[128]; float gb3[4];
};

// packed a += s * {wx,wy} -> v_pk_fma_f32. v2f ONLY as named locals (R6 lesson).
__device__ __forceinline__ v2f pkfma(float s, float wx, float wy, v2f a) {
  v2f w = {wx, wy};
  v2f sv = {s, s};
  return __builtin_elementwise_fma(sv, w, a);
}

__device__ __forceinline__ float ftanh(float x) {
  // tanh(x) = 1 - 2/(exp(2x)+1); exp->inf => rcp->0 => 1. Asymptotes exact.
  float e = __expf(x + x);
  float r = __builtin_amdgcn_rcpf(e + 1.0f);
  return fmaf(-2.0f, r, 1.0f);
}

// LayerNorm over 32 values held 8-per-lane across a 4-lane quad.
// g/b are row-remapped: my row (8p+i) lives at slot i*4+p.
__device__ __forceinline__ void lnorm8_quad(float* t, const float* g,
                                            const float* b, int p) {
  float s = 0.f, ss = 0.f;
  #pragma unroll
  for (int i = 0; i < 8; ++i) { s += t[i]; ss = fmaf(t[i], t[i], ss); }
  s  += __shfl_xor(s, 1);  ss += __shfl_xor(ss, 1);
  s  += __shfl_xor(s, 2);  ss += __shfl_xor(ss, 2);
  float m = s * 0.03125f;
  float v = fmaf(-m, m, ss * 0.03125f);
  float r = __frsqrt_rn(v + EPSV);
  #pragma unroll
  for (int i = 0; i < 8; ++i) t[i] = fmaf((t[i] - m) * r, g[i * 4 + p], b[i * 4 + p]);
}

// f-eval split across a 4-lane quad: lane p owns cols [8p, 8p+8) of each
// 32-wide layer. Fences every <=8 float4 loads keep peak VGPR demand < 128
// so the allocator's 128-target (4 waves/SIMD) is spill-free (R10 lesson:
// 16-load windows overshoot 128 -> residual spill -> 115 GB scratch traffic).
__device__ __forceinline__ void fode4(const WS* w, int p, const float y[4],
                                      float out[4]) {
  const float4* W1v  = (const float4*)w->W1;
  const float4* b1v  = (const float4*)w->b1;
  const float4* W2v  = (const float4*)w->W2;   // row-remapped
  const float4* G1v  = (const float4*)w->G1;
  const float4* gb1v = (const float4*)w->gb1;
  const float4* G2v  = (const float4*)w->G2;
  const float4* gb2v = (const float4*)w->gb2;
  const float4* G3v  = (const float4*)w->G3;   // row-remapped
  const int j0 = 2 * p;   // my float4 col-group base (of 8)
  const int r0 = 8 * p;   // my row base (of 32)

  // ---- magnitude net: partial over my 8 hidden units ----
  v2f m0 = {0.f, 0.f}, m1 = {0.f, 0.f};
  #pragma unroll
  for (int j = 0; j < 2; ++j) {
    float4 bb = b1v[j0 + j];
    v2f a0 = {bb.x, bb.y}, a1 = {bb.z, bb.w};
    #pragma unroll
    for (int i = 0; i < 4; ++i) {
      float4 wv = W1v[i * 8 + j0 + j];
      a0 = pkfma(y[i], wv.x, wv.y, a0);
      a1 = pkfma(y[i], wv.z, wv.w, a1);
    }
    SBAR();   // close W1-load window before W2 loads open
    float h0 = ftanh(a0.x), h1 = ftanh(a0.y), h2 = ftanh(a1.x), h3 = ftanh(a1.y);
    // original W2 row (8p + 4j + c) -> remapped slot (4j+c)*4 + p
    float4 w0 = W2v[(4*j + 0) * 4 + p];
    m0 = pkfma(h0, w0.x, w0.y, m0); m1 = pkfma(h0, w0.z, w0.w, m1);
    float4 w1 = W2v[(4*j + 1) * 4 + p];
    m0 = pkfma(h1, w1.x, w1.y, m0); m1 = pkfma(h1, w1.z, w1.w, m1);
    float4 w2 = W2v[(4*j + 2) * 4 + p];
    m0 = pkfma(h2, w2.x, w2.y, m0); m1 = pkfma(h2, w2.z, w2.w, m1);
    float4 w3 = W2v[(4*j + 3) * 4 + p];
    m0 = pkfma(h3, w3.x, w3.y, m0); m1 = pkfma(h3, w3.z, w3.w, m1);
    SBAR();
  }

  // ---- gating layer 1: my 8 of t = LN(tanh(y@G1+gb1)) ----
  float tm[8];
  #pragma unroll
  for (int j = 0; j < 2; ++j) {
    float4 bb = gb1v[j0 + j];
    v2f a0 = {bb.x, bb.y}, a1 = {bb.z, bb.w};
    #pragma unroll
    for (int i = 0; i < 4; ++i) {
      float4 wv = G1v[i * 8 + j0 + j];
      a0 = pkfma(y[i], wv.x, wv.y, a0);
      a1 = pkfma(y[i], wv.z, wv.w, a1);
    }
    tm[4*j+0] = ftanh(a0.x); tm[4*j+1] = ftanh(a0.y);
    tm[4*j+2] = ftanh(a1.x); tm[4*j+3] = ftanh(a1.y);
    SBAR();
  }
  lnorm8_quad(tm, w->l1g, w->l1b, p);

  // ---- gating layer 2: my 8 of u = LN(tanh(t@G2+gb2)) ----
  float um[8];
  {
    float4 bb0 = gb2v[j0], bb1 = gb2v[j0 + 1];
    v2f a00 = {bb0.x, bb0.y}, a01 = {bb0.z, bb0.w};
    v2f a10 = {bb1.x, bb1.y}, a11 = {bb1.z, bb1.w};
    #pragma unroll
    for (int m = 0; m < 4; ++m) {
      const int rq = r0 ^ (8 * m);   // partner (p^m)'s row base -- address only
      #pragma unroll
      for (int i = 0; i < 8; ++i) {
        float s = (m == 0) ? tm[i] : __shfl_xor(tm[i], m);
        float4 w0 = G2v[(rq + i) * 8 + j0];
        a00 = pkfma(s, w0.x, w0.y, a00); a01 = pkfma(s, w0.z, w0.w, a01);
        float4 w1 = G2v[(rq + i) * 8 + j0 + 1];
        a10 = pkfma(s, w1.x, w1.y, a10); a11 = pkfma(s, w1.z, w1.w, a11);
        if (i == 3) SBAR();   // cap window at 8 float4 (32 VGPRs)
      }
      SBAR();
    }
    um[0] = ftanh(a00.x); um[1] = ftanh(a00.y);
    um[2] = ftanh(a01.x); um[3] = ftanh(a01.y);
    um[4] = ftanh(a10.x); um[5] = ftanh(a10.y);
    um[6] = ftanh(a11.x); um[7] = ftanh(a11.y);
  }
  lnorm8_quad(um, w->l2g, w->l2b, p);

  // ---- G3 partial over my 8 rows, then quad-reduce ----
  v2f z0 = {0.f, 0.f}, z1 = {0.f, 0.f};
  #pragma unroll
  for (int i = 0; i < 8; ++i) {
    float4 wv = G3v[i * 4 + p];   // remapped slot for row 8p+i
    z0 = pkfma(um[i], wv.x, wv.y, z0);
    z1 = pkfma(um[i], wv.z, wv.w, z1);
    if (i == 3) SBAR();
  }
  SBAR();

  float4 b2v  = *(const float4*)w->b2;
  float4 gb3v = *(const float4*)w->gb3;
  float zx = z0.x, zy = z0.y, zz = z1.x, zw = z1.y;
  float mx = m0.x, my = m0.y, mz = m1.x, mw = m1.y;
  zx += __shfl_xor(zx, 1); zx += __shfl_xor(zx, 2);
  zy += __shfl_xor(zy, 1); zy += __shfl_xor(zy, 2);
  zz += __shfl_xor(zz, 1); zz += __shfl_xor(zz, 2);
  zw += __shfl_xor(zw, 1); zw += __shfl_xor(zw, 2);
  mx += __shfl_xor(mx, 1); mx += __shfl_xor(mx, 2);
  my += __shfl_xor(my, 1); my += __shfl_xor(my, 2);
  mz += __shfl_xor(mz, 1); mz += __shfl_xor(mz, 2);
  mw += __shfl_xor(mw, 1); mw += __shfl_xor(mw, 2);
  zx += gb3v.x; zy += gb3v.y; zz += gb3v.z; zw += gb3v.w;
  out[0] = (mx + b2v.x) * __expf(-zx * zx);
  out[1] = (my + b2v.y) * __expf(-zy * zy);
  out[2] = (mz + b2v.z) * __expf(-zz * zz);
  out[3] = (mw + b2v.w) * __expf(-zw * zw);
}

__global__ __launch_bounds__(256, 2) void ode_kernel(
    const float* __restrict__ s_grid, const float* __restrict__ y0,
    const float* __restrict__ W1, const float* __restrict__ b1,
    const float* __restrict__ W2, const float* __restrict__ b2,
    const float* __restrict__ G1, const float* __restrict__ gb1,
    const float* __restrict__ l1g, const float* __restrict__ l1b,
    const float* __restrict__ G2, const float* __restrict__ gb2,
    const float* __restrict__ l2g, const float* __restrict__ l2b,
    const float* __restrict__ G3, const float* __restrict__ gb3,
    float* __restrict__ out, int T, int B) {
  __shared__ WS w;
  __shared__ float sg[512];
  const int tx = threadIdx.x;

  for (int i = tx; i < 128; i += 256) { w.W1[i] = W1[i]; w.G1[i] = G1[i]; }
  for (int i = tx; i < 1024; i += 256) w.G2[i] = G2[i];
  if (tx < 32) {
    const int d = (tx & 7) * 4 + (tx >> 3);   // row remap
    ((float4*)w.W2)[d] = ((const float4*)W2)[tx];
    ((float4*)w.G3)[d] = ((const float4*)G3)[tx];
    w.l1g[d] = l1g[tx]; w.l1b[d] = l1b[tx];
    w.l2g[d] = l2g[tx]; w.l2b[d] = l2b[tx];
    w.b1[tx] = b1[tx];  w.gb1[tx] = gb1[tx]; w.gb2[tx] = gb2[tx];
  }
  if (tx < 4) { w.b2[tx] = b2[tx]; w.gb3[tx] = gb3[tx]; }
  for (int i = tx; i < T && i < 512; i += 256) sg[i] = s_grid[i];
  __syncthreads();

  const int tid = blockIdx.x * 256 + tx;
  const int sys = tid >> 2;   // one system per 4-lane quad
  const int p   = tid & 3;    // my column/row quarter
  if (sys >= B) return;

  float4 y0v = ((const float4*)y0)[sys];
  float y[4] = {y0v.x, y0v.y, y0v.z, y0v.w};

  // coalesced component store: lane p stores component p at flat idx t*4B+tid
  {
    float yv = (p == 0) ? y[0] : ((p == 1) ? y[1] : ((p == 2) ? y[2] : y[3]));
    out[tid] = yv;
  }

  #pragma unroll 1
  for (int t = 0; t < T - 1; ++t) {
    const float h = sg[t + 1] - sg[t];
    float k[4], ksum[4], yt[4];

    fode4(&w, p, y, k);
    #pragma unroll
    for (int c = 0; c < 4; ++c) { ksum[c] = k[c]; yt[c] = fmaf(0.5f * h, k[c], y[c]); }
    SBAR();
    fode4(&w, p, yt, k);
    #pragma unroll
    for (int c = 0; c < 4; ++c) { ksum[c] = fmaf(2.0f, k[c], ksum[c]); yt[c] = fmaf(0.5f * h, k[c], y[c]); }
    SBAR();
    fode4(&w, p, yt, k);
    #pragma unroll
    for (int c = 0; c < 4; ++c) { ksum[c] = fmaf(2.0f, k[c], ksum[c]); yt[c] = fmaf(h, k[c], y[c]); }
    SBAR();
    fode4(&w, p, yt, k);
    #pragma unroll
    for (int c = 0; c < 4; ++c)
      y[c] = fmaf(h * (1.0f / 6.0f), ksum[c] + k[c], y[c]);

    float yv = (p == 0) ? y[0] : ((p == 1) ? y[1] : ((p == 2) ? y[2] : y[3]));
    out[(size_t)(t + 1) * 4 * B + tid] = yv;
  }
}

extern "C" void kernel_launch(void* const* d_in, const int* in_sizes, int n_in,
                              void* d_out, int out_size, void* d_ws, size_t ws_size,
                              hipStream_t stream) {
  const float* s_grid = (const float*)d_in[0];
  const float* y0     = (const float*)d_in[1];
  const float* W1     = (const float*)d_in[2];
  const float* b1     = (const float*)d_in[3];
  const float* W2     = (const float*)d_in[4];
  const float* b2     = (const float*)d_in[5];
  const float* G1     = (const float*)d_in[6];
  const float* gb1    = (const float*)d_in[7];
  const float* l1g    = (const float*)d_in[8];
  const float* l1b    = (const float*)d_in[9];
  const float* G2     = (const float*)d_in[10];
  const float* gb2    = (const float*)d_in[11];
  const float* l2g    = (const float*)d_in[12];
  const float* l2b    = (const float*)d_in[13];
  const float* G3     = (const float*)d_in[14];
  const float* gb3    = (const float*)d_in[15];

  const int T = in_sizes[0];
  const int B = in_sizes[1] / 4;

  const long long threads = 4LL * B;   // 4 lanes per system -> 4 waves/SIMD
  dim3 block(256);
  dim3 grid((unsigned)((threads + 255) / 256));
  hipLaunchKernelGGL(ode_kernel, grid, block, 0, stream,
                     s_grid, y0, W1, b1, W2, b2, G1, gb1, l1g, l1b,
                     G2, gb2, l2g, l2b, G3, gb3, (float*)d_out, T, B);
}

// Round 12
// 5429.707 us; speedup vs baseline: 17.4947x; 1.1549x over previous
//
#include <hip/hip_runtime.h>
#include <math.h>

typedef float v2f __attribute__((ext_vector_type(2)));

#define EPSV 1e-5f
#define SBAR() __builtin_amdgcn_sched_barrier(0)

// Cross-lane within a 4-lane quad via DPP quad_perm (pure VALU, 1 cyc).
// __shfl_xor lowers to ds_bpermute_b32 (LDS pipe + lgkmcnt wait) -- R11's
// ~56 shuffles/eval were LDS-pipe ops in serial reduce chains.
template <int CTRL>
__device__ __forceinline__ float qp(float x) {
  return __int_as_float(
      __builtin_amdgcn_update_dpp(0, __float_as_int(x), CTRL, 0xF, 0xF, true));
}
#define XOR1(x) qp<0xB1>(x)   // quad_perm [1,0,3,2]
#define XOR2(x) qp<0x4E>(x)   // quad_perm [2,3,0,1]
#define XOR3(x) qp<0x1B>(x)   // quad_perm [3,2,1,0]

// W2, G3, l1g/l1b/l2g/l2b stored ROW-REMAPPED in LDS: row r -> slot
// (r&7)*4 + (r>>3): quad lanes read 16B apart -> conflict-free (R9/R10).
struct __align__(16) WS {
  float W1[128]; float b1[32]; float W2[128]; float b2[4];
  float G1[128]; float gb1[32]; float l1g[32]; float l1b[32];
  float G2[1024]; float gb2[32]; float l2g[32]; float l2b[32];
  float G3[128]; float gb3[4];
};

// packed a += s * {wx,wy} -> v_pk_fma_f32. v2f ONLY as named locals (R6 lesson).
__device__ __forceinline__ v2f pkfma(float s, float wx, float wy, v2f a) {
  v2f w = {wx, wy};
  v2f sv = {s, s};
  return __builtin_elementwise_fma(sv, w, a);
}

__device__ __forceinline__ float ftanh(float x) {
  // tanh(x) = 1 - 2/(exp(2x)+1); exp->inf => rcp->0 => 1. Asymptotes exact.
  float e = __expf(x + x);
  float r = __builtin_amdgcn_rcpf(e + 1.0f);
  return fmaf(-2.0f, r, 1.0f);
}

// LayerNorm over 32 values held 8-per-lane across a 4-lane quad (DPP reduce).
__device__ __forceinline__ void lnorm8_quad(float* t, const float* g,
                                            const float* b, int p) {
  float s = 0.f, ss = 0.f;
  #pragma unroll
  for (int i = 0; i < 8; ++i) { s += t[i]; ss = fmaf(t[i], t[i], ss); }
  s += XOR1(s);  ss += XOR1(ss);
  s += XOR2(s);  ss += XOR2(ss);
  float m = s * 0.03125f;
  float v = fmaf(-m, m, ss * 0.03125f);
  float r = __frsqrt_rn(v + EPSV);
  #pragma unroll
  for (int i = 0; i < 8; ++i) t[i] = fmaf((t[i] - m) * r, g[i * 4 + p], b[i * 4 + p]);
}

// f-eval split across a 4-lane quad: lane p owns cols [8p, 8p+8). Partner
// t-values arrive via DPP VALUE + partner row base in the LDS ADDRESS.
__device__ __forceinline__ void fode4(const WS* w, int p, const float y[4],
                                      float out[4]) {
  const float4* W1v  = (const float4*)w->W1;
  const float4* b1v  = (const float4*)w->b1;
  const float4* W2v  = (const float4*)w->W2;   // row-remapped
  const float4* G1v  = (const float4*)w->G1;
  const float4* gb1v = (const float4*)w->gb1;
  const float4* G2v  = (const float4*)w->G2;
  const float4* gb2v = (const float4*)w->gb2;
  const float4* G3v  = (const float4*)w->G3;   // row-remapped
  const int j0 = 2 * p;   // my float4 col-group base (of 8)
  const int r0 = 8 * p;   // my row base (of 32)

  // ---- magnitude net: partial over my 8 hidden units ----
  v2f m0 = {0.f, 0.f}, m1 = {0.f, 0.f};
  #pragma unroll
  for (int j = 0; j < 2; ++j) {
    float4 bb = b1v[j0 + j];
    v2f a0 = {bb.x, bb.y}, a1 = {bb.z, bb.w};
    #pragma unroll
    for (int i = 0; i < 4; ++i) {
      float4 wv = W1v[i * 8 + j0 + j];
      a0 = pkfma(y[i], wv.x, wv.y, a0);
      a1 = pkfma(y[i], wv.z, wv.w, a1);
    }
    SBAR();   // close W1-load window before W2 loads open
    float h0 = ftanh(a0.x), h1 = ftanh(a0.y), h2 = ftanh(a1.x), h3 = ftanh(a1.y);
    float4 w0 = W2v[(4*j + 0) * 4 + p];
    m0 = pkfma(h0, w0.x, w0.y, m0); m1 = pkfma(h0, w0.z, w0.w, m1);
    float4 w1 = W2v[(4*j + 1) * 4 + p];
    m0 = pkfma(h1, w1.x, w1.y, m0); m1 = pkfma(h1, w1.z, w1.w, m1);
    float4 w2 = W2v[(4*j + 2) * 4 + p];
    m0 = pkfma(h2, w2.x, w2.y, m0); m1 = pkfma(h2, w2.z, w2.w, m1);
    float4 w3 = W2v[(4*j + 3) * 4 + p];
    m0 = pkfma(h3, w3.x, w3.y, m0); m1 = pkfma(h3, w3.z, w3.w, m1);
    SBAR();
  }

  // ---- gating layer 1: my 8 of t = LN(tanh(y@G1+gb1)) ----
  float tm[8];
  #pragma unroll
  for (int j = 0; j < 2; ++j) {
    float4 bb = gb1v[j0 + j];
    v2f a0 = {bb.x, bb.y}, a1 = {bb.z, bb.w};
    #pragma unroll
    for (int i = 0; i < 4; ++i) {
      float4 wv = G1v[i * 8 + j0 + j];
      a0 = pkfma(y[i], wv.x, wv.y, a0);
      a1 = pkfma(y[i], wv.z, wv.w, a1);
    }
    tm[4*j+0] = ftanh(a0.x); tm[4*j+1] = ftanh(a0.y);
    tm[4*j+2] = ftanh(a1.x); tm[4*j+3] = ftanh(a1.y);
    SBAR();
  }
  lnorm8_quad(tm, w->l1g, w->l1b, p);

  // ---- gating layer 2: my 8 of u = LN(tanh(t@G2+gb2)) ----
  // 4 m-groups hand-unrolled so DPP ctrl is a literal; partner rows go in
  // the LDS address (r0 ^ 8m), partner values via DPP.
  float um[8];
  {
    float4 bb0 = gb2v[j0], bb1 = gb2v[j0 + 1];
    v2f a00 = {bb0.x, bb0.y}, a01 = {bb0.z, bb0.w};
    v2f a10 = {bb1.x, bb1.y}, a11 = {bb1.z, bb1.w};

#define G2_GROUP(RQ, GETS)                                        \
    _Pragma("unroll")                                             \
    for (int i = 0; i < 8; ++i) {                                 \
      float s = (GETS);                                           \
      float4 w0 = G2v[((RQ) + i) * 8 + j0];                       \
      a00 = pkfma(s, w0.x, w0.y, a00); a01 = pkfma(s, w0.z, w0.w, a01); \
      float4 w1 = G2v[((RQ) + i) * 8 + j0 + 1];                   \
      a10 = pkfma(s, w1.x, w1.y, a10); a11 = pkfma(s, w1.z, w1.w, a11); \
      if (i == 3) SBAR();                                         \
    }                                                             \
    SBAR();

    G2_GROUP(r0,        tm[i])
    G2_GROUP(r0 ^ 8,    XOR1(tm[i]))
    G2_GROUP(r0 ^ 16,   XOR2(tm[i]))
    G2_GROUP(r0 ^ 24,   XOR3(tm[i]))
#undef G2_GROUP

    um[0] = ftanh(a00.x); um[1] = ftanh(a00.y);
    um[2] = ftanh(a01.x); um[3] = ftanh(a01.y);
    um[4] = ftanh(a10.x); um[5] = ftanh(a10.y);
    um[6] = ftanh(a11.x); um[7] = ftanh(a11.y);
  }
  lnorm8_quad(um, w->l2g, w->l2b, p);

  // ---- G3 partial over my 8 rows, then quad-reduce (DPP) ----
  v2f z0 = {0.f, 0.f}, z1 = {0.f, 0.f};
  #pragma unroll
  for (int i = 0; i < 8; ++i) {
    float4 wv = G3v[i * 4 + p];   // remapped slot for row 8p+i
    z0 = pkfma(um[i], wv.x, wv.y, z0);
    z1 = pkfma(um[i], wv.z, wv.w, z1);
    if (i == 3) SBAR();
  }
  SBAR();

  float4 b2v  = *(const float4*)w->b2;
  float4 gb3v = *(const float4*)w->gb3;
  float zx = z0.x, zy = z0.y, zz = z1.x, zw = z1.y;
  float mx = m0.x, my = m0.y, mz = m1.x, mw = m1.y;
  zx += XOR1(zx); zx += XOR2(zx);
  zy += XOR1(zy); zy += XOR2(zy);
  zz += XOR1(zz); zz += XOR2(zz);
  zw += XOR1(zw); zw += XOR2(zw);
  mx += XOR1(mx); mx += XOR2(mx);
  my += XOR1(my); my += XOR2(my);
  mz += XOR1(mz); mz += XOR2(mz);
  mw += XOR1(mw); mw += XOR2(mw);
  zx += gb3v.x; zy += gb3v.y; zz += gb3v.z; zw += gb3v.w;
  out[0] = (mx + b2v.x) * __expf(-zx * zx);
  out[1] = (my + b2v.y) * __expf(-zy * zy);
  out[2] = (mz + b2v.z) * __expf(-zz * zz);
  out[3] = (mw + b2v.w) * __expf(-zw * zw);
}

__global__ __launch_bounds__(256, 2) void ode_kernel(
    const float* __restrict__ s_grid, const float* __restrict__ y0,
    const float* __restrict__ W1, const float* __restrict__ b1,
    const float* __restrict__ W2, const float* __restrict__ b2,
    const float* __restrict__ G1, const float* __restrict__ gb1,
    const float* __restrict__ l1g, const float* __restrict__ l1b,
    const float* __restrict__ G2, const float* __restrict__ gb2,
    const float* __restrict__ l2g, const float* __restrict__ l2b,
    const float* __restrict__ G3, const float* __restrict__ gb3,
    float* __restrict__ out, int T, int B) {
  __shared__ WS w;
  __shared__ float sg[512];
  const int tx = threadIdx.x;

  for (int i = tx; i < 128; i += 256) { w.W1[i] = W1[i]; w.G1[i] = G1[i]; }
  for (int i = tx; i < 1024; i += 256) w.G2[i] = G2[i];
  if (tx < 32) {
    const int d = (tx & 7) * 4 + (tx >> 3);   // row remap
    ((float4*)w.W2)[d] = ((const float4*)W2)[tx];
    ((float4*)w.G3)[d] = ((const float4*)G3)[tx];
    w.l1g[d] = l1g[tx]; w.l1b[d] = l1b[tx];
    w.l2g[d] = l2g[tx]; w.l2b[d] = l2b[tx];
    w.b1[tx] = b1[tx];  w.gb1[tx] = gb1[tx]; w.gb2[tx] = gb2[tx];
  }
  if (tx < 4) { w.b2[tx] = b2[tx]; w.gb3[tx] = gb3[tx]; }
  for (int i = tx; i < T && i < 512; i += 256) sg[i] = s_grid[i];
  __syncthreads();

  const int tid = blockIdx.x * 256 + tx;
  const int sys = tid >> 2;   // one system per 4-lane quad
  const int p   = tid & 3;    // my column/row quarter
  if (sys >= B) return;

  float4 y0v = ((const float4*)y0)[sys];
  float y[4] = {y0v.x, y0v.y, y0v.z, y0v.w};

  // coalesced component store: lane p stores component p at flat idx t*4B+tid
  {
    float yv = (p == 0) ? y[0] : ((p == 1) ? y[1] : ((p == 2) ? y[2] : y[3]));
    out[tid] = yv;
  }

  #pragma unroll 1
  for (int t = 0; t < T - 1; ++t) {
    const float h = sg[t + 1] - sg[t];
    float k[4], ksum[4], yt[4];

    fode4(&w, p, y, k);
    #pragma unroll
    for (int c = 0; c < 4; ++c) { ksum[c] = k[c]; yt[c] = fmaf(0.5f * h, k[c], y[c]); }
    SBAR();
    fode4(&w, p, yt, k);
    #pragma unroll
    for (int c = 0; c < 4; ++c) { ksum[c] = fmaf(2.0f, k[c], ksum[c]); yt[c] = fmaf(0.5f * h, k[c], y[c]); }
    SBAR();
    fode4(&w, p, yt, k);
    #pragma unroll
    for (int c = 0; c < 4; ++c) { ksum[c] = fmaf(2.0f, k[c], ksum[c]); yt[c] = fmaf(h, k[c], y[c]); }
    SBAR();
    fode4(&w, p, yt, k);
    #pragma unroll
    for (int c = 0; c < 4; ++c)
      y[c] = fmaf(h * (1.0f / 6.0f), ksum[c] + k[c], y[c]);

    float yv = (p == 0) ? y[0] : ((p == 1) ? y[1] : ((p == 2) ? y[2] : y[3]));
    out[(size_t)(t + 1) * 4 * B + tid] = yv;
  }
}

extern "C" void kernel_launch(void* const* d_in, const int* in_sizes, int n_in,
                              void* d_out, int out_size, void* d_ws, size_t ws_size,
                              hipStream_t stream) {
  const float* s_grid = (const float*)d_in[0];
  const float* y0     = (const float*)d_in[1];
  const float* W1     = (const float*)d_in[2];
  const float* b1     = (const float*)d_in[3];
  const float* W2     = (const float*)d_in[4];
  const float* b2     = (const float*)d_in[5];
  const float* G1     = (const float*)d_in[6];
  const float* gb1    = (const float*)d_in[7];
  const float* l1g    = (const float*)d_in[8];
  const float* l1b    = (const float*)d_in[9];
  const float* G2     = (const float*)d_in[10];
  const float* gb2    = (const float*)d_in[11];
  const float* l2g    = (const float*)d_in[12];
  const float* l2b    = (const float*)d_in[13];
  const float* G3     = (const float*)d_in[14];
  const float* gb3    = (const float*)d_in[15];

  const int T = in_sizes[0];
  const int B = in_sizes[1] / 4;

  const long long threads = 4LL * B;   // 4 lanes per system
  dim3 block(256);
  dim3 grid((unsigned)((threads + 255) / 256));
  hipLaunchKernelGGL(ode_kernel, grid, block, 0, stream,
                     s_grid, y0, W1, b1, W2, b2, G1, gb1, l1g, l1b,
                     G2, gb2, l2g, l2b, G3, gb3, (float*)d_out, T, B);
}

// Round 13
// 4738.481 us; speedup vs baseline: 20.0467x; 1.1459x over previous
//
#include <hip/hip_runtime.h>
#include <math.h>

typedef float v2f __attribute__((ext_vector_type(2)));

#define EPSV 1e-5f
#define SBAR() __builtin_amdgcn_sched_barrier(0)

// Cross-lane within a 4-lane quad via DPP quad_perm (pure VALU, 1 cyc).
template <int CTRL>
__device__ __forceinline__ float qp(float x) {
  return __int_as_float(
      __builtin_amdgcn_update_dpp(0, __float_as_int(x), CTRL, 0xF, 0xF, true));
}
#define XOR1(x) qp<0xB1>(x)   // quad_perm [1,0,3,2]
#define XOR2(x) qp<0x4E>(x)   // quad_perm [2,3,0,1]
#define XOR3(x) qp<0x1B>(x)   // quad_perm [3,2,1,0]

// Weights staged with ALGEBRAIC FOLDS (R13):
//  * W1,b1,G1,gb1 pre-scaled by 2*log2(e): tanh's exp(2a)=exp2(a') needs no
//    per-eval multiply.
//  * G2 rows pre-scaled by l1g AND 2*log2(e); gb2 += l1b@G2 (LN1 affine fold).
//  * G3 rows pre-scaled by l2g; gb3 += l2b@G3 (LN2 affine fold).
//  LNs in-kernel are pure normalize: t = (x-m)*rsqrt(v+eps).
// W2, G3 row-remapped: row r -> slot (r&7)*4+(r>>3) (quad conflict-free).
struct __align__(16) WS {
  float W1[128]; float b1[32]; float W2[128]; float b2[4];
  float G1[128]; float gb1[32];
  float G2[1024]; float gb2[32];
  float G3[128]; float gb3[4];
};

// packed a += s * {wx,wy} -> v_pk_fma_f32. v2f ONLY as named locals (R6 lesson).
__device__ __forceinline__ v2f pkfma(float s, float wx, float wy, v2f a) {
  v2f w = {wx, wy};
  v2f sv = {s, s};
  return __builtin_elementwise_fma(sv, w, a);
}

// tanh from PRE-SCALED arg: a = 2*log2(e)*x. tanh(x)=1-2/(exp2(a)+1).
// a->+inf: exp2->inf, rcp->0 => 1; a->-inf: exp2->0, rcp(1)=1 => -1. Exact.
__device__ __forceinline__ float ftanhp(float a) {
  float e = __builtin_amdgcn_exp2f(a);
  float r = __builtin_amdgcn_rcpf(e + 1.0f);
  return fmaf(-2.0f, r, 1.0f);
}

// Pure normalize over 32 values held 8-per-lane across a quad (DPP reduce).
__device__ __forceinline__ void lnz8_quad(float* t) {
  float s = 0.f, ss = 0.f;
  #pragma unroll
  for (int i = 0; i < 8; ++i) { s += t[i]; ss = fmaf(t[i], t[i], ss); }
  s += XOR1(s);  ss += XOR1(ss);
  s += XOR2(s);  ss += XOR2(ss);
  float m = s * 0.03125f;
  float v = fmaf(-m, m, ss * 0.03125f);
  float r = __frsqrt_rn(v + EPSV);
  float nmr = -m * r;
  #pragma unroll
  for (int i = 0; i < 8; ++i) t[i] = fmaf(t[i], r, nmr);
}

// f-eval split across a 4-lane quad: lane p owns cols [8p, 8p+8). Partner
// t-values arrive via DPP VALUE + partner row base in the LDS ADDRESS.
__device__ __forceinline__ void fode4(const WS* w, int p, const float y[4],
                                      float out[4]) {
  const float4* W1v  = (const float4*)w->W1;
  const float4* b1v  = (const float4*)w->b1;
  const float4* W2v  = (const float4*)w->W2;   // row-remapped
  const float4* G1v  = (const float4*)w->G1;
  const float4* gb1v = (const float4*)w->gb1;
  const float4* G2v  = (const float4*)w->G2;
  const float4* gb2v = (const float4*)w->gb2;
  const float4* G3v  = (const float4*)w->G3;   // row-remapped, l2g-scaled
  const int j0 = 2 * p;   // my float4 col-group base (of 8)
  const int r0 = 8 * p;   // my row base (of 32)

  // ---- magnitude net: partial over my 8 hidden units ----
  v2f m0 = {0.f, 0.f}, m1 = {0.f, 0.f};
  #pragma unroll
  for (int j = 0; j < 2; ++j) {
    float4 bb = b1v[j0 + j];
    v2f a0 = {bb.x, bb.y}, a1 = {bb.z, bb.w};
    #pragma unroll
    for (int i = 0; i < 4; ++i) {
      float4 wv = W1v[i * 8 + j0 + j];
      a0 = pkfma(y[i], wv.x, wv.y, a0);
      a1 = pkfma(y[i], wv.z, wv.w, a1);
    }
    SBAR();   // close W1-load window before W2 loads open
    float h0 = ftanhp(a0.x), h1 = ftanhp(a0.y), h2 = ftanhp(a1.x), h3 = ftanhp(a1.y);
    float4 w0 = W2v[(4*j + 0) * 4 + p];
    m0 = pkfma(h0, w0.x, w0.y, m0); m1 = pkfma(h0, w0.z, w0.w, m1);
    float4 w1 = W2v[(4*j + 1) * 4 + p];
    m0 = pkfma(h1, w1.x, w1.y, m0); m1 = pkfma(h1, w1.z, w1.w, m1);
    float4 w2 = W2v[(4*j + 2) * 4 + p];
    m0 = pkfma(h2, w2.x, w2.y, m0); m1 = pkfma(h2, w2.z, w2.w, m1);
    float4 w3 = W2v[(4*j + 3) * 4 + p];
    m0 = pkfma(h3, w3.x, w3.y, m0); m1 = pkfma(h3, w3.z, w3.w, m1);
    SBAR();
  }

  // ---- gating layer 1: my 8 of t = normalize(tanh(y@G1+gb1)) ----
  float tm[8];
  #pragma unroll
  for (int j = 0; j < 2; ++j) {
    float4 bb = gb1v[j0 + j];
    v2f a0 = {bb.x, bb.y}, a1 = {bb.z, bb.w};
    #pragma unroll
    for (int i = 0; i < 4; ++i) {
      float4 wv = G1v[i * 8 + j0 + j];
      a0 = pkfma(y[i], wv.x, wv.y, a0);
      a1 = pkfma(y[i], wv.z, wv.w, a1);
    }
    tm[4*j+0] = ftanhp(a0.x); tm[4*j+1] = ftanhp(a0.y);
    tm[4*j+2] = ftanhp(a1.x); tm[4*j+3] = ftanhp(a1.y);
    SBAR();
  }
  lnz8_quad(tm);

  // ---- gating layer 2: my 8 of u = normalize(tanh(t@G2'+gb2')) ----
  float um[8];
  {
    float4 bb0 = gb2v[j0], bb1 = gb2v[j0 + 1];
    v2f a00 = {bb0.x, bb0.y}, a01 = {bb0.z, bb0.w};
    v2f a10 = {bb1.x, bb1.y}, a11 = {bb1.z, bb1.w};

#define G2_GROUP(RQ, GETS)                                        \
    _Pragma("unroll")                                             \
    for (int i = 0; i < 8; ++i) {                                 \
      float s = (GETS);                                           \
      float4 w0 = G2v[((RQ) + i) * 8 + j0];                       \
      a00 = pkfma(s, w0.x, w0.y, a00); a01 = pkfma(s, w0.z, w0.w, a01); \
      float4 w1 = G2v[((RQ) + i) * 8 + j0 + 1];                   \
      a10 = pkfma(s, w1.x, w1.y, a10); a11 = pkfma(s, w1.z, w1.w, a11); \
      if (i == 3) SBAR();                                         \
    }                                                             \
    SBAR();

    G2_GROUP(r0,        tm[i])
    G2_GROUP(r0 ^ 8,    XOR1(tm[i]))
    G2_GROUP(r0 ^ 16,   XOR2(tm[i]))
    G2_GROUP(r0 ^ 24,   XOR3(tm[i]))
#undef G2_GROUP

    um[0] = ftanhp(a00.x); um[1] = ftanhp(a00.y);
    um[2] = ftanhp(a01.x); um[3] = ftanhp(a01.y);
    um[4] = ftanhp(a10.x); um[5] = ftanhp(a10.y);
    um[6] = ftanhp(a11.x); um[7] = ftanhp(a11.y);
  }
  lnz8_quad(um);

  // ---- G3' partial over my 8 rows, then quad-reduce (DPP) ----
  v2f z0 = {0.f, 0.f}, z1 = {0.f, 0.f};
  #pragma unroll
  for (int i = 0; i < 8; ++i) {
    float4 wv = G3v[i * 4 + p];   // remapped slot for row 8p+i
    z0 = pkfma(um[i], wv.x, wv.y, z0);
    z1 = pkfma(um[i], wv.z, wv.w, z1);
    if (i == 3) SBAR();
  }
  SBAR();

  const float NL2E = -1.4426950408889634f;  // -log2(e)
  float4 b2v  = *(const float4*)w->b2;
  float4 gb3v = *(const float4*)w->gb3;
  float zx = z0.x, zy = z0.y, zz = z1.x, zw = z1.y;
  float mx = m0.x, my = m0.y, mz = m1.x, mw = m1.y;
  zx += XOR1(zx); zx += XOR2(zx);
  zy += XOR1(zy); zy += XOR2(zy);
  zz += XOR1(zz); zz += XOR2(zz);
  zw += XOR1(zw); zw += XOR2(zw);
  mx += XOR1(mx); mx += XOR2(mx);
  my += XOR1(my); my += XOR2(my);
  mz += XOR1(mz); mz += XOR2(mz);
  mw += XOR1(mw); mw += XOR2(mw);
  zx += gb3v.x; zy += gb3v.y; zz += gb3v.z; zw += gb3v.w;
  out[0] = (mx + b2v.x) * __builtin_amdgcn_exp2f(NL2E * zx * zx);
  out[1] = (my + b2v.y) * __builtin_amdgcn_exp2f(NL2E * zy * zy);
  out[2] = (mz + b2v.z) * __builtin_amdgcn_exp2f(NL2E * zz * zz);
  out[3] = (mw + b2v.w) * __builtin_amdgcn_exp2f(NL2E * zw * zw);
}

__global__ __launch_bounds__(256, 2) void ode_kernel(
    const float* __restrict__ s_grid, const float* __restrict__ y0,
    const float* __restrict__ W1, const float* __restrict__ b1,
    const float* __restrict__ W2, const float* __restrict__ b2,
    const float* __restrict__ G1, const float* __restrict__ gb1,
    const float* __restrict__ l1g, const float* __restrict__ l1b,
    const float* __restrict__ G2, const float* __restrict__ gb2,
    const float* __restrict__ l2g, const float* __restrict__ l2b,
    const float* __restrict__ G3, const float* __restrict__ gb3,
    float* __restrict__ out, int T, int B) {
  __shared__ WS w;
  __shared__ float sg[512];
  const int tx = threadIdx.x;
  const float TL2E = 2.8853900817779268f;   // 2*log2(e)

  for (int i = tx; i < 128; i += 256) {
    w.W1[i] = W1[i] * TL2E;
    w.G1[i] = G1[i] * TL2E;
  }
  // G2' = (l1g o rows of G2) * 2log2e  (LN1 affine + tanh-arg fold)
  for (int i = tx; i < 1024; i += 256) w.G2[i] = G2[i] * l1g[i >> 5] * TL2E;
  if (tx < 32) {
    const int d = (tx & 7) * 4 + (tx >> 3);   // row remap
    ((float4*)w.W2)[d] = ((const float4*)W2)[tx];
    float4 g3 = ((const float4*)G3)[tx];
    const float s3 = l2g[tx];                 // LN2 affine fold (scale)
    g3.x *= s3; g3.y *= s3; g3.z *= s3; g3.w *= s3;
    ((float4*)w.G3)[d] = g3;
    w.b1[tx]  = b1[tx]  * TL2E;
    w.gb1[tx] = gb1[tx] * TL2E;
    float acc = gb2[tx];                      // LN1 affine fold (bias)
    for (int r = 0; r < 32; ++r) acc = fmaf(l1b[r], G2[r * 32 + tx], acc);
    w.gb2[tx] = acc * TL2E;
  }
  if (tx < 4) {
    w.b2[tx] = b2[tx];
    float acc = gb3[tx];                      // LN2 affine fold (bias)
    for (int r = 0; r < 32; ++r) acc = fmaf(l2b[r], G3[r * 4 + tx], acc);
    w.gb3[tx] = acc;
  }
  for (int i = tx; i < T && i < 512; i += 256) sg[i] = s_grid[i];
  __syncthreads();

  const int tid = blockIdx.x * 256 + tx;
  const int sys = tid >> 2;   // one system per 4-lane quad
  const int p   = tid & 3;    // my column/row quarter
  if (sys >= B) return;

  float4 y0v = ((const float4*)y0)[sys];
  float y[4] = {y0v.x, y0v.y, y0v.z, y0v.w};

  // coalesced component store: lane p stores component p at flat idx t*4B+tid
  {
    float yv = (p == 0) ? y[0] : ((p == 1) ? y[1] : ((p == 2) ? y[2] : y[3]));
    out[tid] = yv;
  }

  #pragma unroll 1
  for (int t = 0; t < T - 1; ++t) {
    const float h = sg[t + 1] - sg[t];
    float k[4], ksum[4], yt[4];

    fode4(&w, p, y, k);
    #pragma unroll
    for (int c = 0; c < 4; ++c) { ksum[c] = k[c]; yt[c] = fmaf(0.5f * h, k[c], y[c]); }
    SBAR();
    fode4(&w, p, yt, k);
    #pragma unroll
    for (int c = 0; c < 4; ++c) { ksum[c] = fmaf(2.0f, k[c], ksum[c]); yt[c] = fmaf(0.5f * h, k[c], y[c]); }
    SBAR();
    fode4(&w, p, yt, k);
    #pragma unroll
    for (int c = 0; c < 4; ++c) { ksum[c] = fmaf(2.0f, k[c], ksum[c]); yt[c] = fmaf(h, k[c], y[c]); }
    SBAR();
    fode4(&w, p, yt, k);
    #pragma unroll
    for (int c = 0; c < 4; ++c)
      y[c] = fmaf(h * (1.0f / 6.0f), ksum[c] + k[c], y[c]);

    float yv = (p == 0) ? y[0] : ((p == 1) ? y[1] : ((p == 2) ? y[2] : y[3]));
    out[(size_t)(t + 1) * 4 * B + tid] = yv;
  }
}

extern "C" void kernel_launch(void* const* d_in, const int* in_sizes, int n_in,
                              void* d_out, int out_size, void* d_ws, size_t ws_size,
                              hipStream_t stream) {
  const float* s_grid = (const float*)d_in[0];
  const float* y0     = (const float*)d_in[1];
  const float* W1     = (const float*)d_in[2];
  const float* b1     = (const float*)d_in[3];
  const float* W2     = (const float*)d_in[4];
  const float* b2     = (const float*)d_in[5];
  const float* G1     = (const float*)d_in[6];
  const float* gb1    = (const float*)d_in[7];
  const float* l1g    = (const float*)d_in[8];
  const float* l1b    = (const float*)d_in[9];
  const float* G2     = (const float*)d_in[10];
  const float* gb2    = (const float*)d_in[11];
  const float* l2g    = (const float*)d_in[12];
  const float* l2b    = (const float*)d_in[13];
  const float* G3     = (const float*)d_in[14];
  const float* gb3    = (const float*)d_in[15];

  const int T = in_sizes[0];
  const int B = in_sizes[1] / 4;

  const long long threads = 4LL * B;   // 4 lanes per system
  dim3 block(256);
  dim3 grid((unsigned)((threads + 255) / 256));
  hipLaunchKernelGGL(ode_kernel, grid, block, 0, stream,
                     s_grid, y0, W1, b1, W2, b2, G1, gb1, l1g, l1b,
                     G2, gb2, l2g, l2b, G3, gb3, (float*)d_out, T, B);
}